// Round 3
// baseline (863.798 us; speedup 1.0000x reference)
//
#include <hip/hip_runtime.h>
#include <math.h>

#define NSB  512   // edge-chunk blocks for hist/bucket passes
#define BSH  8     // 256 nodes per bucket
#define SPLIT 4    // edge slices per bucket in aggregation

// ================= generic exclusive scan (n <= 524288) =================

__global__ void k_scan1(const int* __restrict__ in, int* __restrict__ out,
                        int* __restrict__ bsum, int n) {
    __shared__ int sd[256];
    int base = blockIdx.x * 2048 + threadIdx.x * 8;
    int v[8];
    int ts = 0;
#pragma unroll
    for (int j = 0; j < 8; j++) {
        int idx = base + j;
        v[j] = ts;
        ts += (idx < n) ? in[idx] : 0;
    }
    sd[threadIdx.x] = ts;
    __syncthreads();
    for (int ofs = 1; ofs < 256; ofs <<= 1) {
        int t = (threadIdx.x >= (unsigned)ofs) ? sd[threadIdx.x - ofs] : 0;
        __syncthreads();
        sd[threadIdx.x] += t;
        __syncthreads();
    }
    int excl = (threadIdx.x == 0) ? 0 : sd[threadIdx.x - 1];
#pragma unroll
    for (int j = 0; j < 8; j++) {
        int idx = base + j;
        if (idx < n) out[idx] = excl + v[j];
    }
    if (threadIdx.x == 255) bsum[blockIdx.x] = sd[255];
}

__global__ void k_scan2(int* __restrict__ bsum, int nb) {
    __shared__ int sd[256];
    int orig = (threadIdx.x < (unsigned)nb) ? bsum[threadIdx.x] : 0;
    sd[threadIdx.x] = orig;
    __syncthreads();
    for (int ofs = 1; ofs < 256; ofs <<= 1) {
        int t = (threadIdx.x >= (unsigned)ofs) ? sd[threadIdx.x - ofs] : 0;
        __syncthreads();
        sd[threadIdx.x] += t;
        __syncthreads();
    }
    if (threadIdx.x < (unsigned)nb) bsum[threadIdx.x] = sd[threadIdx.x] - orig;
}

__global__ void k_scan3(int* __restrict__ out, const int* __restrict__ bsum, int n) {
    int i = blockIdx.x * blockDim.x + threadIdx.x;
    if (i < n) out[i] += bsum[i >> 11];
}

// ================= bucketing (256-node buckets) =================

__global__ void k_hist(const int* __restrict__ dst, int* __restrict__ hist,
                       int e, int nbuck, int es) {
    __shared__ int h[512];
    for (int i = threadIdx.x; i < 512; i += blockDim.x) h[i] = 0;
    __syncthreads();
    int lo = blockIdx.x * es;
    int hi = min(lo + es, e);
    for (int i = lo + threadIdx.x; i < hi; i += blockDim.x)
        atomicAdd(&h[dst[i] >> BSH], 1);
    __syncthreads();
    for (int i = threadIdx.x; i < nbuck; i += blockDim.x)
        hist[(size_t)i * gridDim.x + blockIdx.x] = h[i];
}

__global__ void k_bucket(const int* __restrict__ src, const int* __restrict__ dst,
                         const int* __restrict__ offs, unsigned* __restrict__ col,
                         int e, int nbuck, int es) {
    __shared__ int cur[512];
    for (int i = threadIdx.x; i < nbuck; i += blockDim.x)
        cur[i] = offs[(size_t)i * gridDim.x + blockIdx.x];
    __syncthreads();
    int lo = blockIdx.x * es;
    int hi = min(lo + es, e);
    for (int i = lo + threadIdx.x; i < hi; i += blockDim.x) {
        int d = dst[i];
        int b = d >> BSH;
        int pos = atomicAdd(&cur[b], 1);
        col[pos] = ((unsigned)src[i] << BSH) | (unsigned)(d & 255);
    }
}

__global__ void k_deg(const unsigned* __restrict__ col, const int* __restrict__ offs,
                      float* __restrict__ dis, int n, int e, int nbuck) {
    __shared__ int cnt[256];
    cnt[threadIdx.x] = 0;
    __syncthreads();
    int b = blockIdx.x;
    int lo = offs[(size_t)b * NSB];
    int hi = (b + 1 < nbuck) ? offs[(size_t)(b + 1) * NSB] : e;
    for (int i = lo + threadIdx.x; i < hi; i += blockDim.x)
        atomicAdd(&cnt[col[i] & 255], 1);
    __syncthreads();
    int node = (b << BSH) + threadIdx.x;
    if (node < n) dis[node] = rsqrtf((float)(cnt[threadIdx.x] + 1));
}

// ================= linears (write hs_scaled AND seed accumulator) =================

__global__ void k_linear1s(const float* __restrict__ x, const float* __restrict__ W,
                           const float* __restrict__ dis, float* __restrict__ hs,
                           float* __restrict__ outinit, int n) {
    __shared__ float sW[128 * 16];
    for (int i = threadIdx.x; i < 128 * 16; i += blockDim.x) sW[i] = W[i];
    __syncthreads();
    int t = blockIdx.x * blockDim.x + threadIdx.x;
    int node = t >> 4, c = t & 15;
    if (node >= n) return;
    const float* xr = x + (size_t)node * 128;
    float acc = 0.f;
#pragma unroll 8
    for (int k = 0; k < 128; k++) acc += xr[k] * sW[k * 16 + c];
    float v = acc * dis[node];
    hs[(size_t)node * 16 + c] = v;
    outinit[(size_t)node * 16 + c] = v;
}

__global__ void k_brl16s(const float* __restrict__ in, const float* __restrict__ b,
                         const float* __restrict__ W, const float* __restrict__ dis,
                         float* __restrict__ hs, float* __restrict__ outinit, int n) {
    __shared__ float sW[256];
    __shared__ float sb[16];
    if (threadIdx.x < 256) sW[threadIdx.x] = W[threadIdx.x];
    if (threadIdx.x < 16) sb[threadIdx.x] = b[threadIdx.x];
    __syncthreads();
    int t = blockIdx.x * blockDim.x + threadIdx.x;
    int node = t >> 4, c = t & 15;
    if (node >= n) return;
    float d = dis[node];
    const float* ir = in + (size_t)node * 16;
    float acc = 0.f;
#pragma unroll
    for (int k = 0; k < 16; k++) {
        float v = ir[k] * d + sb[k];
        v = v > 0.f ? v : 0.f;
        acc += v * sW[k * 16 + c];
    }
    float o = acc * d;
    hs[(size_t)node * 16 + c] = o;
    outinit[(size_t)node * 16 + c] = o;
}

__global__ void k_brl2s(const float* __restrict__ in, const float* __restrict__ b,
                        const float* __restrict__ W, const float* __restrict__ dis,
                        float* __restrict__ hs2, float* __restrict__ outinit, int n) {
    int node = blockIdx.x * blockDim.x + threadIdx.x;
    if (node >= n) return;
    float d = dis[node];
    const float* ir = in + (size_t)node * 16;
    float a0 = 0.f, a1 = 0.f;
#pragma unroll
    for (int k = 0; k < 16; k++) {
        float v = ir[k] * d + b[k];
        v = v > 0.f ? v : 0.f;
        a0 += v * W[k * 2 + 0];
        a1 += v * W[k * 2 + 1];
    }
    a0 *= d; a1 *= d;
    hs2[(size_t)node * 2 + 0] = a0;
    hs2[(size_t)node * 2 + 1] = a1;
    outinit[(size_t)node * 2 + 0] = a0;
    outinit[(size_t)node * 2 + 1] = a1;
}

// ================= bucketed aggregation: LDS accumulate + dense flush =================

__global__ void k_agg16(const float* __restrict__ hs, const unsigned* __restrict__ col,
                        const int* __restrict__ offs, float* __restrict__ out,
                        int n, int e, int nbuck) {
    __shared__ float acc[256 * 16];
    for (int i = threadIdx.x; i < 4096; i += 256) acc[i] = 0.f;
    __syncthreads();
    int b = blockIdx.x >> 2, s = blockIdx.x & 3;
    int lo = offs[(size_t)b * NSB];
    int hi = (b + 1 < nbuck) ? offs[(size_t)(b + 1) * NSB] : e;
    int len = hi - lo;
    int cs = (len + SPLIT - 1) >> 2;
    int l2 = lo + s * cs;
    int h2 = min(l2 + cs, hi);
    int c = threadIdx.x & 15, eo = threadIdx.x >> 4;
    for (int i = l2 + eo; i < h2; i += 16) {
        unsigned v = col[i];
        int sn = (int)(v >> BSH), dl = (int)(v & 255u);
        atomicAdd(&acc[dl * 16 + c], hs[(size_t)sn * 16 + c]);
    }
    __syncthreads();
    int base = (b << BSH) * 16;
    int lim = n * 16;
    for (int i = threadIdx.x; i < 4096; i += 256) {
        int gi = base + i;
        if (gi < lim) {
            float v = acc[i];
            if (v != 0.f) atomicAdd(&out[gi], v);
        }
    }
}

__global__ void k_agg2(const float* __restrict__ hs2, const unsigned* __restrict__ col,
                       const int* __restrict__ offs, float* __restrict__ out,
                       int n, int e, int nbuck) {
    __shared__ float acc[256 * 2];
    for (int i = threadIdx.x; i < 512; i += 256) acc[i] = 0.f;
    __syncthreads();
    int b = blockIdx.x >> 2, s = blockIdx.x & 3;
    int lo = offs[(size_t)b * NSB];
    int hi = (b + 1 < nbuck) ? offs[(size_t)(b + 1) * NSB] : e;
    int len = hi - lo;
    int cs = (len + SPLIT - 1) >> 2;
    int l2 = lo + s * cs;
    int h2 = min(l2 + cs, hi);
    int c = threadIdx.x & 1, eo = threadIdx.x >> 1;
    for (int i = l2 + eo; i < h2; i += 128) {
        unsigned v = col[i];
        int sn = (int)(v >> BSH), dl = (int)(v & 255u);
        atomicAdd(&acc[dl * 2 + c], hs2[(size_t)sn * 2 + c]);
    }
    __syncthreads();
    int base = (b << BSH) * 2;
    int lim = n * 2;
    for (int i = threadIdx.x; i < 512; i += 256) {
        int gi = base + i;
        if (gi < lim) {
            float v = acc[i];
            if (v != 0.f) atomicAdd(&out[gi], v);
        }
    }
}

// ================= bias + log_softmax (folds dis scaling) =================

__global__ void k_lsm(const float* __restrict__ in, const float* __restrict__ b,
                      const float* __restrict__ dis, float* __restrict__ out, int n) {
    int node = blockIdx.x * blockDim.x + threadIdx.x;
    if (node >= n) return;
    float d = dis[node];
    float z0 = in[(size_t)node * 2 + 0] * d + b[0];
    float z1 = in[(size_t)node * 2 + 1] * d + b[1];
    float m = fmaxf(z0, z1);
    float l = m + logf(expf(z0 - m) + expf(z1 - m));
    out[(size_t)node * 2 + 0] = z0 - l;
    out[(size_t)node * 2 + 1] = z1 - l;
}

// ================= launch =================

extern "C" void kernel_launch(void* const* d_in, const int* in_sizes, int n_in,
                              void* d_out, int out_size, void* d_ws, size_t ws_size,
                              hipStream_t stream) {
    const float* x  = (const float*)d_in[0];
    const int*   ei = (const int*)d_in[1];
    const float* W1 = (const float*)d_in[2];
    const float* b1 = (const float*)d_in[3];
    const float* W2 = (const float*)d_in[4];
    const float* b2 = (const float*)d_in[5];
    const float* W3 = (const float*)d_in[6];
    const float* b3 = (const float*)d_in[7];
    float* out = (float*)d_out;

    const int N = in_sizes[0] / 128;
    const int E = in_sizes[1] / 2;
    const int* src = ei;
    const int* dst = ei + E;

    const int NBUCK = (N + 255) >> BSH;
    const int M = NBUCK * NSB;
    const int ES = (E + NSB - 1) / NSB;

    char* ws = (char*)d_ws;
    size_t off = 0;
    auto alloc = [&](size_t bytes) {
        void* p = ws + off;
        off += (bytes + 255) & ~(size_t)255;
        return p;
    };
    int*      hist = (int*)alloc((size_t)M * sizeof(int));
    int*      offs = (int*)alloc((size_t)M * sizeof(int));
    int*      bsum = (int*)alloc(256 * sizeof(int));
    unsigned* col  = (unsigned*)alloc((size_t)E * sizeof(unsigned));
    float*    dis  = (float*)alloc((size_t)N * sizeof(float));
    float*    bufA = (float*)alloc((size_t)N * 16 * sizeof(float));
    float*    bufB = (float*)alloc((size_t)N * 16 * sizeof(float));
    float*    bufE = (float*)alloc((size_t)N * 16 * sizeof(float));
    float*    bufC = (float*)alloc((size_t)N * 2 * sizeof(float));
    float*    bufD = (float*)alloc((size_t)N * 2 * sizeof(float));

    const int B = 256;
    auto g = [&](long long work) { return (int)((work + B - 1) / B); };
    const int NBS = (M + 2047) / 2048;

    // ---- bucket build ----
    k_hist<<<NSB, B, 0, stream>>>(dst, hist, E, NBUCK, ES);
    k_scan1<<<NBS, 256, 0, stream>>>(hist, offs, bsum, M);
    k_scan2<<<1, 256, 0, stream>>>(bsum, NBS);
    k_scan3<<<g(M), B, 0, stream>>>(offs, bsum, M);
    k_bucket<<<NSB, B, 0, stream>>>(src, dst, offs, col, E, NBUCK, ES);
    k_deg<<<NBUCK, 256, 0, stream>>>(col, offs, dis, N, E, NBUCK);

    // ---- layer 1: hs->bufA, accum seeded in bufB ----
    k_linear1s<<<g((long long)N * 16), B, 0, stream>>>(x, W1, dis, bufA, bufB, N);
    k_agg16<<<NBUCK * SPLIT, B, 0, stream>>>(bufA, col, offs, bufB, N, E, NBUCK);

    // ---- layer 2: reads bufB, hs->bufA, accum seeded in bufE ----
    k_brl16s<<<g((long long)N * 16), B, 0, stream>>>(bufB, b1, W2, dis, bufA, bufE, N);
    k_agg16<<<NBUCK * SPLIT, B, 0, stream>>>(bufA, col, offs, bufE, N, E, NBUCK);

    // ---- layer 3: reads bufE, hs->bufC, accum seeded in bufD ----
    k_brl2s<<<g(N), B, 0, stream>>>(bufE, b2, W3, dis, bufC, bufD, N);
    k_agg2<<<NBUCK * SPLIT, B, 0, stream>>>(bufC, col, offs, bufD, N, E, NBUCK);

    // ---- log_softmax ----
    k_lsm<<<g(N), B, 0, stream>>>(bufD, b3, dis, out, N);
}

// Round 4
// 351.839 us; speedup vs baseline: 2.4551x; 2.4551x over previous
//
#include <hip/hip_runtime.h>
#include <math.h>

#define NSB  512   // edge-chunk blocks for hist/bucket passes
#define BSH  8     // 256 nodes per bucket

// ================= exclusive scan (n <= 524288) =================

__global__ void k_scan1(const int* __restrict__ in, int* __restrict__ out,
                        int* __restrict__ bsum, int n) {
    __shared__ int sd[256];
    int base = blockIdx.x * 2048 + threadIdx.x * 8;
    int v[8];
    int ts = 0;
#pragma unroll
    for (int j = 0; j < 8; j++) {
        int idx = base + j;
        v[j] = ts;
        ts += (idx < n) ? in[idx] : 0;
    }
    sd[threadIdx.x] = ts;
    __syncthreads();
    for (int ofs = 1; ofs < 256; ofs <<= 1) {
        int t = (threadIdx.x >= (unsigned)ofs) ? sd[threadIdx.x - ofs] : 0;
        __syncthreads();
        sd[threadIdx.x] += t;
        __syncthreads();
    }
    int excl = (threadIdx.x == 0) ? 0 : sd[threadIdx.x - 1];
#pragma unroll
    for (int j = 0; j < 8; j++) {
        int idx = base + j;
        if (idx < n) out[idx] = excl + v[j];
    }
    if (threadIdx.x == 255) bsum[blockIdx.x] = sd[255];
}

__global__ void k_scan2(int* __restrict__ bsum, int nb) {
    __shared__ int sd[256];
    int orig = (threadIdx.x < (unsigned)nb) ? bsum[threadIdx.x] : 0;
    sd[threadIdx.x] = orig;
    __syncthreads();
    for (int ofs = 1; ofs < 256; ofs <<= 1) {
        int t = (threadIdx.x >= (unsigned)ofs) ? sd[threadIdx.x - ofs] : 0;
        __syncthreads();
        sd[threadIdx.x] += t;
        __syncthreads();
    }
    if (threadIdx.x < (unsigned)nb) bsum[threadIdx.x] = sd[threadIdx.x] - orig;
}

__global__ void k_scan3(int* __restrict__ out, const int* __restrict__ bsum, int n) {
    int i = blockIdx.x * blockDim.x + threadIdx.x;
    if (i < n) out[i] += bsum[i >> 11];
}

// ================= bucketing (256-node buckets) =================

__global__ void k_hist(const int* __restrict__ dst, int* __restrict__ hist,
                       int e, int nbuck, int es) {
    __shared__ int h[512];
    for (int i = threadIdx.x; i < 512; i += blockDim.x) h[i] = 0;
    __syncthreads();
    int lo = blockIdx.x * es;
    int hi = min(lo + es, e);
    for (int i = lo + threadIdx.x; i < hi; i += blockDim.x)
        atomicAdd(&h[dst[i] >> BSH], 1);
    __syncthreads();
    for (int i = threadIdx.x; i < nbuck; i += blockDim.x)
        hist[(size_t)i * gridDim.x + blockIdx.x] = h[i];
}

// deterministic scatter into bucket-grouped edge array, packed (src<<8)|dstLocal
__global__ void k_bucket(const int* __restrict__ src, const int* __restrict__ dst,
                         const int* __restrict__ offs, unsigned* __restrict__ col,
                         int e, int nbuck, int es) {
    __shared__ int cur[512];
    for (int i = threadIdx.x; i < nbuck; i += blockDim.x)
        cur[i] = offs[(size_t)i * gridDim.x + blockIdx.x];
    __syncthreads();
    int lo = blockIdx.x * es;
    int hi = min(lo + es, e);
    for (int i = lo + threadIdx.x; i < hi; i += blockDim.x) {
        int d = dst[i];
        int b = d >> BSH;
        int pos = atomicAdd(&cur[b], 1);
        col[pos] = ((unsigned)src[i] << BSH) | (unsigned)(d & 255);
    }
}

// per-bucket counting sort by dstLocal -> exact CSR (col2 = src ids, rs = row starts),
// plus degree -> dis. One block per bucket, blockDim = 256.
__global__ void k_sort(const unsigned* __restrict__ col, const int* __restrict__ offs,
                       int* __restrict__ col2, int* __restrict__ rs,
                       float* __restrict__ dis, int n, int e, int nbuck) {
    __shared__ int cnt[256];
    __shared__ int sd[256];
    __shared__ int cur[256];
    int tid = threadIdx.x;
    int b = blockIdx.x;
    int lo = offs[(size_t)b * NSB];
    int hi = (b + 1 < nbuck) ? offs[(size_t)(b + 1) * NSB] : e;
    cnt[tid] = 0;
    __syncthreads();
    for (int i = lo + tid; i < hi; i += 256)
        atomicAdd(&cnt[col[i] & 255u], 1);
    __syncthreads();
    // inclusive scan of cnt -> sd
    sd[tid] = cnt[tid];
    __syncthreads();
    for (int ofs = 1; ofs < 256; ofs <<= 1) {
        int t = (tid >= ofs) ? sd[tid - ofs] : 0;
        __syncthreads();
        sd[tid] += t;
        __syncthreads();
    }
    int excl = (tid == 0) ? 0 : sd[tid - 1];
    cur[tid] = lo + excl;
    int node = (b << BSH) + tid;
    if (node < n) {
        rs[node] = lo + excl;
        dis[node] = rsqrtf((float)(cnt[tid] + 1));
    }
    if (b == 0 && tid == 0) rs[n] = e;
    __syncthreads();
    for (int i = lo + tid; i < hi; i += 256) {
        unsigned v = col[i];
        int pos = atomicAdd(&cur[v & 255u], 1);
        col2[pos] = (int)(v >> BSH);
    }
}

// ================= linears (output pre-scaled by dis[node]) =================

// hs[n,16] = (x[n,128] @ W[128,16]) * dis[n]; block handles 16 nodes, x staged in LDS
__global__ void k_linear1s(const float* __restrict__ x, const float* __restrict__ W,
                           const float* __restrict__ dis, float* __restrict__ hs, int n) {
    __shared__ float sW[128 * 16];
    __shared__ float sx[16 * 129];   // padded stride to dodge bank conflicts
    int tid = threadIdx.x;
    for (int i = tid; i < 128 * 16; i += 256) sW[i] = W[i];
    int nodeBase = blockIdx.x * 16;
    for (int i = tid; i < 2048; i += 256) {
        int nl = i >> 7, k = i & 127;
        int nd = nodeBase + nl;
        sx[nl * 129 + k] = (nd < n) ? x[(size_t)nd * 128 + k] : 0.f;
    }
    __syncthreads();
    int nl = tid >> 4, c = tid & 15;
    int node = nodeBase + nl;
    if (node >= n) return;
    const float* xr = sx + nl * 129;
    float acc = 0.f;
#pragma unroll 8
    for (int k = 0; k < 128; k++) acc += xr[k] * sW[k * 16 + c];
    hs[(size_t)node * 16 + c] = acc * dis[node];
}

// hs[n,16] = (relu(in[n,16]+b) @ W[16,16]) * dis[n]   (in = final aggregated values)
__global__ void k_brl16s(const float* __restrict__ in, const float* __restrict__ b,
                         const float* __restrict__ W, const float* __restrict__ dis,
                         float* __restrict__ hs, int n) {
    __shared__ float sW[256];
    __shared__ float sb[16];
    if (threadIdx.x < 256) sW[threadIdx.x] = W[threadIdx.x];
    if (threadIdx.x < 16) sb[threadIdx.x] = b[threadIdx.x];
    __syncthreads();
    int t = blockIdx.x * blockDim.x + threadIdx.x;
    int node = t >> 4, c = t & 15;
    if (node >= n) return;
    const float* ir = in + (size_t)node * 16;
    float acc = 0.f;
#pragma unroll
    for (int k = 0; k < 16; k++) {
        float v = ir[k] + sb[k];
        v = v > 0.f ? v : 0.f;
        acc += v * sW[k * 16 + c];
    }
    hs[(size_t)node * 16 + c] = acc * dis[node];
}

// hs2[n,2] = (relu(in[n,16]+b) @ W[16,2]) * dis[n]
__global__ void k_brl2s(const float* __restrict__ in, const float* __restrict__ b,
                        const float* __restrict__ W, const float* __restrict__ dis,
                        float* __restrict__ hs2, int n) {
    int node = blockIdx.x * blockDim.x + threadIdx.x;
    if (node >= n) return;
    const float* ir = in + (size_t)node * 16;
    float a0 = 0.f, a1 = 0.f;
#pragma unroll
    for (int k = 0; k < 16; k++) {
        float v = ir[k] + b[k];
        v = v > 0.f ? v : 0.f;
        a0 += v * W[k * 2 + 0];
        a1 += v * W[k * 2 + 1];
    }
    float d = dis[node];
    hs2[(size_t)node * 2 + 0] = a0 * d;
    hs2[(size_t)node * 2 + 1] = a1 * d;
}

// ================= pull aggregation (no atomics, float4) =================
// out[n,c] = (hs[n,c] + sum_{s in in(n)} hs[s,c]) * dis[n]; 4 threads per node

__global__ void k_pull16(const float* __restrict__ hs, const int* __restrict__ rs,
                         const int* __restrict__ col2, const float* __restrict__ dis,
                         float* __restrict__ out, int n) {
    int t = blockIdx.x * blockDim.x + threadIdx.x;
    int node = t >> 2, q = t & 3;
    if (node >= n) return;
    const float4* h4 = (const float4*)hs;
    float4 acc = h4[(size_t)node * 4 + q];
    int b = rs[node], e2 = rs[node + 1];
    int i = b;
    for (; i + 3 < e2; i += 4) {
        int s0 = col2[i], s1 = col2[i + 1], s2 = col2[i + 2], s3 = col2[i + 3];
        float4 v0 = h4[(size_t)s0 * 4 + q];
        float4 v1 = h4[(size_t)s1 * 4 + q];
        float4 v2 = h4[(size_t)s2 * 4 + q];
        float4 v3 = h4[(size_t)s3 * 4 + q];
        acc.x += v0.x + v1.x + v2.x + v3.x;
        acc.y += v0.y + v1.y + v2.y + v3.y;
        acc.z += v0.z + v1.z + v2.z + v3.z;
        acc.w += v0.w + v1.w + v2.w + v3.w;
    }
    for (; i < e2; i++) {
        int s = col2[i];
        float4 v = h4[(size_t)s * 4 + q];
        acc.x += v.x; acc.y += v.y; acc.z += v.z; acc.w += v.w;
    }
    float d = dis[node];
    acc.x *= d; acc.y *= d; acc.z *= d; acc.w *= d;
    ((float4*)out)[(size_t)node * 4 + q] = acc;
}

__global__ void k_pull2(const float* __restrict__ hs2, const int* __restrict__ rs,
                        const int* __restrict__ col2, const float* __restrict__ dis,
                        float* __restrict__ out, int n) {
    int node = blockIdx.x * blockDim.x + threadIdx.x;
    if (node >= n) return;
    const float2* h2 = (const float2*)hs2;
    float2 acc = h2[node];
    int b = rs[node], e2 = rs[node + 1];
    for (int i = b; i < e2; i++) {
        float2 v = h2[col2[i]];
        acc.x += v.x; acc.y += v.y;
    }
    float d = dis[node];
    acc.x *= d; acc.y *= d;
    ((float2*)out)[node] = acc;
}

// ================= bias + log_softmax (C=2) =================

__global__ void k_lsm(const float* __restrict__ in, const float* __restrict__ b,
                      float* __restrict__ out, int n) {
    int node = blockIdx.x * blockDim.x + threadIdx.x;
    if (node >= n) return;
    float z0 = in[(size_t)node * 2 + 0] + b[0];
    float z1 = in[(size_t)node * 2 + 1] + b[1];
    float m = fmaxf(z0, z1);
    float l = m + logf(expf(z0 - m) + expf(z1 - m));
    out[(size_t)node * 2 + 0] = z0 - l;
    out[(size_t)node * 2 + 1] = z1 - l;
}

// ================= launch =================

extern "C" void kernel_launch(void* const* d_in, const int* in_sizes, int n_in,
                              void* d_out, int out_size, void* d_ws, size_t ws_size,
                              hipStream_t stream) {
    const float* x  = (const float*)d_in[0];
    const int*   ei = (const int*)d_in[1];
    const float* W1 = (const float*)d_in[2];
    const float* b1 = (const float*)d_in[3];
    const float* W2 = (const float*)d_in[4];
    const float* b2 = (const float*)d_in[5];
    const float* W3 = (const float*)d_in[6];
    const float* b3 = (const float*)d_in[7];
    float* out = (float*)d_out;

    const int N = in_sizes[0] / 128;
    const int E = in_sizes[1] / 2;
    const int* src = ei;
    const int* dst = ei + E;

    const int NBUCK = (N + 255) >> BSH;          // 391
    const int M = NBUCK * NSB;                   // per-(bucket,block) offsets
    const int ES = (E + NSB - 1) / NSB;

    char* ws = (char*)d_ws;
    size_t off = 0;
    auto alloc = [&](size_t bytes) {
        void* p = ws + off;
        off += (bytes + 255) & ~(size_t)255;
        return p;
    };
    int*      hist = (int*)alloc((size_t)M * sizeof(int));
    int*      offs = (int*)alloc((size_t)M * sizeof(int));
    int*      bsum = (int*)alloc(256 * sizeof(int));
    unsigned* col  = (unsigned*)alloc((size_t)E * sizeof(unsigned));
    int*      col2 = (int*)alloc((size_t)E * sizeof(int));
    int*      rs   = (int*)alloc((size_t)(N + 1) * sizeof(int));
    float*    dis  = (float*)alloc((size_t)N * sizeof(float));
    float*    bufA = (float*)alloc((size_t)N * 16 * sizeof(float));
    float*    bufB = (float*)alloc((size_t)N * 16 * sizeof(float));
    float*    bufC = (float*)alloc((size_t)N * 2 * sizeof(float));
    float*    bufD = (float*)alloc((size_t)N * 2 * sizeof(float));

    const int B = 256;
    auto g = [&](long long work) { return (int)((work + B - 1) / B); };
    const int NBS = (M + 2047) / 2048;

    // ---- CSR build via bucketing + per-bucket counting sort ----
    k_hist<<<NSB, B, 0, stream>>>(dst, hist, E, NBUCK, ES);
    k_scan1<<<NBS, 256, 0, stream>>>(hist, offs, bsum, M);
    k_scan2<<<1, 256, 0, stream>>>(bsum, NBS);
    k_scan3<<<g(M), B, 0, stream>>>(offs, bsum, M);
    k_bucket<<<NSB, B, 0, stream>>>(src, dst, offs, col, E, NBUCK, ES);
    k_sort<<<NBUCK, 256, 0, stream>>>(col, offs, col2, rs, dis, N, E, NBUCK);

    // ---- layer 1 ----
    k_linear1s<<<(N + 15) / 16, B, 0, stream>>>(x, W1, dis, bufA, N);
    k_pull16<<<g((long long)N * 4), B, 0, stream>>>(bufA, rs, col2, dis, bufB, N);

    // ---- layer 2 ----
    k_brl16s<<<g((long long)N * 16), B, 0, stream>>>(bufB, b1, W2, dis, bufA, N);
    k_pull16<<<g((long long)N * 4), B, 0, stream>>>(bufA, rs, col2, dis, bufB, N);

    // ---- layer 3 ----
    k_brl2s<<<g(N), B, 0, stream>>>(bufB, b2, W3, dis, bufC, N);
    k_pull2<<<g(N), B, 0, stream>>>(bufC, rs, col2, dis, bufD, N);

    // ---- log_softmax ----
    k_lsm<<<g(N), B, 0, stream>>>(bufD, b3, out, N);
}

// Round 6
// 313.737 us; speedup vs baseline: 2.7533x; 1.1214x over previous
//
#include <hip/hip_runtime.h>
#include <math.h>

#define NSB  256   // edge-chunk blocks for hist/bucket passes
#define BSH  9     // 512 nodes per bucket
#define BKN  512   // nodes per bucket

typedef _Float16 h8  __attribute__((ext_vector_type(8)));
typedef _Float16 h2v __attribute__((ext_vector_type(2)));

// ================= exclusive scan (n <= 524288) =================

__global__ void k_scan1(const int* __restrict__ in, int* __restrict__ out,
                        int* __restrict__ bsum, int n) {
    __shared__ int sd[256];
    int base = blockIdx.x * 2048 + threadIdx.x * 8;
    int v[8];
    int ts = 0;
#pragma unroll
    for (int j = 0; j < 8; j++) {
        int idx = base + j;
        v[j] = ts;
        ts += (idx < n) ? in[idx] : 0;
    }
    sd[threadIdx.x] = ts;
    __syncthreads();
    for (int ofs = 1; ofs < 256; ofs <<= 1) {
        int t = (threadIdx.x >= (unsigned)ofs) ? sd[threadIdx.x - ofs] : 0;
        __syncthreads();
        sd[threadIdx.x] += t;
        __syncthreads();
    }
    int excl = (threadIdx.x == 0) ? 0 : sd[threadIdx.x - 1];
#pragma unroll
    for (int j = 0; j < 8; j++) {
        int idx = base + j;
        if (idx < n) out[idx] = excl + v[j];
    }
    if (threadIdx.x == 255) bsum[blockIdx.x] = sd[255];
}

__global__ void k_scan2(int* __restrict__ bsum, int nb) {
    __shared__ int sd[256];
    int orig = (threadIdx.x < (unsigned)nb) ? bsum[threadIdx.x] : 0;
    sd[threadIdx.x] = orig;
    __syncthreads();
    for (int ofs = 1; ofs < 256; ofs <<= 1) {
        int t = (threadIdx.x >= (unsigned)ofs) ? sd[threadIdx.x - ofs] : 0;
        __syncthreads();
        sd[threadIdx.x] += t;
        __syncthreads();
    }
    if (threadIdx.x < (unsigned)nb) bsum[threadIdx.x] = sd[threadIdx.x] - orig;
}

__global__ void k_scan3(int* __restrict__ out, const int* __restrict__ bsum, int n) {
    int i = blockIdx.x * blockDim.x + threadIdx.x;
    if (i < n) out[i] += bsum[i >> 11];
}

// ================= bucketing (512-node buckets) =================

__global__ void k_hist(const int* __restrict__ dst, int* __restrict__ hist,
                       int e, int nbuck, int es) {
    __shared__ int h[256];
    for (int i = threadIdx.x; i < 256; i += blockDim.x) h[i] = 0;
    __syncthreads();
    int lo = blockIdx.x * es;
    int hi = min(lo + es, e);
    for (int i = lo + threadIdx.x; i < hi; i += blockDim.x)
        atomicAdd(&h[dst[i] >> BSH], 1);
    __syncthreads();
    for (int i = threadIdx.x; i < nbuck; i += blockDim.x)
        hist[(size_t)i * gridDim.x + blockIdx.x] = h[i];
}

// deterministic scatter into bucket-grouped edge array, packed (src<<9)|dstLocal
__global__ void k_bucket(const int* __restrict__ src, const int* __restrict__ dst,
                         const int* __restrict__ offs, unsigned* __restrict__ col,
                         int e, int nbuck, int es) {
    __shared__ int cur[256];
    for (int i = threadIdx.x; i < nbuck; i += blockDim.x)
        cur[i] = offs[(size_t)i * gridDim.x + blockIdx.x];
    __syncthreads();
    int lo = blockIdx.x * es;
    int hi = min(lo + es, e);
    for (int i = lo + threadIdx.x; i < hi; i += blockDim.x) {
        int d = dst[i];
        int b = d >> BSH;
        int pos = atomicAdd(&cur[b], 1);
        col[pos] = ((unsigned)src[i] << BSH) | (unsigned)(d & (BKN - 1));
    }
}

// per-bucket counting sort by dstLocal -> exact CSR (col2 = src ids, rs = row starts),
// plus degree -> dis. One block (512 threads) per bucket.
__global__ void k_sort(const unsigned* __restrict__ col, const int* __restrict__ offs,
                       int* __restrict__ col2, int* __restrict__ rs,
                       float* __restrict__ dis, int n, int e, int nbuck) {
    __shared__ int cnt[BKN];
    __shared__ int sd[BKN];
    __shared__ int cur[BKN];
    int tid = threadIdx.x;
    int b = blockIdx.x;
    int lo = offs[(size_t)b * NSB];
    int hi = (b + 1 < nbuck) ? offs[(size_t)(b + 1) * NSB] : e;
    cnt[tid] = 0;
    __syncthreads();
    for (int i = lo + tid; i < hi; i += BKN)
        atomicAdd(&cnt[col[i] & (BKN - 1u)], 1);
    __syncthreads();
    sd[tid] = cnt[tid];
    __syncthreads();
    for (int ofs = 1; ofs < BKN; ofs <<= 1) {
        int t = (tid >= ofs) ? sd[tid - ofs] : 0;
        __syncthreads();
        sd[tid] += t;
        __syncthreads();
    }
    int excl = (tid == 0) ? 0 : sd[tid - 1];
    cur[tid] = lo + excl;
    int node = (b << BSH) + tid;
    if (node < n) {
        rs[node] = lo + excl;
        dis[node] = rsqrtf((float)(cnt[tid] + 1));
    }
    if (b == 0 && tid == 0) rs[n] = e;
    __syncthreads();
    for (int i = lo + tid; i < hi; i += BKN) {
        unsigned v = col[i];
        int pos = atomicAdd(&cur[v & (BKN - 1u)], 1);
        col2[pos] = (int)(v >> BSH);
    }
}

// ================= layer-1 linear: hs[n,16] = (x @ W1) * dis, fp16 out =================

__global__ void k_linear1s(const float* __restrict__ x, const float* __restrict__ W,
                           const float* __restrict__ dis, _Float16* __restrict__ hs, int n) {
    __shared__ float sW[128 * 16];
    __shared__ float sx[16 * 129];
    int tid = threadIdx.x;
    for (int i = tid; i < 128 * 16; i += 256) sW[i] = W[i];
    int nodeBase = blockIdx.x * 16;
    for (int i = tid; i < 2048; i += 256) {
        int nl = i >> 7, k = i & 127;
        int nd = nodeBase + nl;
        sx[nl * 129 + k] = (nd < n) ? x[(size_t)nd * 128 + k] : 0.f;
    }
    __syncthreads();
    int nl = tid >> 4, c = tid & 15;
    int node = nodeBase + nl;
    if (node >= n) return;
    const float* xr = sx + nl * 129;
    float acc = 0.f;
#pragma unroll 8
    for (int k = 0; k < 128; k++) acc += xr[k] * sW[k * 16 + c];
    hs[(size_t)node * 16 + c] = (_Float16)(acc * dis[node]);
}

// ================= fused pull + 16x16 linear =================
// agg[u] = dis[u]*(hs[u] + sum_{v->u} hs[v]); hsOut[u] = (relu(agg+b) @ W) * dis[u]
// 2 threads per node (q = half of the 16-wide row). Pair-exchange of the 8 relu'd
// activations via shfl_xor(1); each lane then does the full 16-k dot for its 8 outputs.

__global__ void k_pullA(const _Float16* __restrict__ hs, const int* __restrict__ rs,
                        const int* __restrict__ col2, const float* __restrict__ dis,
                        const float* __restrict__ bb, const float* __restrict__ W,
                        _Float16* __restrict__ hsOut, int n) {
    __shared__ float sW[256];
    __shared__ float sb[16];
    if (threadIdx.x < 256) sW[threadIdx.x] = W[threadIdx.x];
    if (threadIdx.x < 16) sb[threadIdx.x] = bb[threadIdx.x];
    __syncthreads();
    int t = blockIdx.x * blockDim.x + threadIdx.x;
    int node = t >> 1, q = t & 1;
    if (node >= n) return;
    const h8* H = (const h8*)hs;
    h8 self = H[(size_t)node * 2 + q];
    float acc[8];
#pragma unroll
    for (int j = 0; j < 8; j++) acc[j] = (float)self[j];
    int b = rs[node], e2 = rs[node + 1];
    int i = b;
    for (; i + 3 < e2; i += 4) {
        int s0 = col2[i], s1 = col2[i + 1], s2 = col2[i + 2], s3 = col2[i + 3];
        h8 v0 = H[(size_t)s0 * 2 + q];
        h8 v1 = H[(size_t)s1 * 2 + q];
        h8 v2 = H[(size_t)s2 * 2 + q];
        h8 v3 = H[(size_t)s3 * 2 + q];
#pragma unroll
        for (int j = 0; j < 8; j++)
            acc[j] += (float)v0[j] + (float)v1[j] + (float)v2[j] + (float)v3[j];
    }
    for (; i < e2; i++) {
        h8 v = H[(size_t)col2[i] * 2 + q];
#pragma unroll
        for (int j = 0; j < 8; j++) acc[j] += (float)v[j];
    }
    float d = dis[node];
    // relu'd activation for own k-range, then assemble full 16-vector via pair exchange
    float va[16];
#pragma unroll
    for (int j = 0; j < 8; j++) {
        int k = q * 8 + j;
        float v = acc[j] * d + sb[k];
        v = v > 0.f ? v : 0.f;
        float other = __shfl_xor(v, 1);
        va[j]     = q ? other : v;      // channel j     (lane q=0's k-range)
        va[8 + j] = q ? v : other;      // channel 8+j   (lane q=1's k-range)
    }
    h8 o;
#pragma unroll
    for (int j = 0; j < 8; j++) {
        int c = q * 8 + j;              // this lane's output channel
        float s = 0.f;
#pragma unroll
        for (int k = 0; k < 16; k++) s += va[k] * sW[k * 16 + c];
        o[j] = (_Float16)(s * d);
    }
    ((h8*)hsOut)[(size_t)node * 2 + q] = o;
}

// ================= fused pull + 16x2 linear (layer 3 transform) =================

__global__ void k_pullB(const _Float16* __restrict__ hs, const int* __restrict__ rs,
                        const int* __restrict__ col2, const float* __restrict__ dis,
                        const float* __restrict__ bb, const float* __restrict__ W,
                        _Float16* __restrict__ hs2, int n) {
    __shared__ float sW[32];
    __shared__ float sb[16];
    if (threadIdx.x < 32) sW[threadIdx.x] = W[threadIdx.x];
    if (threadIdx.x < 16) sb[threadIdx.x] = bb[threadIdx.x];
    __syncthreads();
    int t = blockIdx.x * blockDim.x + threadIdx.x;
    int node = t >> 1, q = t & 1;
    if (node >= n) return;
    const h8* H = (const h8*)hs;
    h8 self = H[(size_t)node * 2 + q];
    float acc[8];
#pragma unroll
    for (int j = 0; j < 8; j++) acc[j] = (float)self[j];
    int b = rs[node], e2 = rs[node + 1];
    int i = b;
    for (; i + 3 < e2; i += 4) {
        int s0 = col2[i], s1 = col2[i + 1], s2 = col2[i + 2], s3 = col2[i + 3];
        h8 v0 = H[(size_t)s0 * 2 + q];
        h8 v1 = H[(size_t)s1 * 2 + q];
        h8 v2 = H[(size_t)s2 * 2 + q];
        h8 v3 = H[(size_t)s3 * 2 + q];
#pragma unroll
        for (int j = 0; j < 8; j++)
            acc[j] += (float)v0[j] + (float)v1[j] + (float)v2[j] + (float)v3[j];
    }
    for (; i < e2; i++) {
        h8 v = H[(size_t)col2[i] * 2 + q];
#pragma unroll
        for (int j = 0; j < 8; j++) acc[j] += (float)v[j];
    }
    float d = dis[node];
    float p0 = 0.f, p1 = 0.f;
#pragma unroll
    for (int j = 0; j < 8; j++) {
        int k = q * 8 + j;
        float v = acc[j] * d + sb[k];
        v = v > 0.f ? v : 0.f;
        p0 += v * sW[k * 2 + 0];
        p1 += v * sW[k * 2 + 1];
    }
    p0 += __shfl_xor(p0, 1);   // same channel on both lanes -> symmetric, safe
    p1 += __shfl_xor(p1, 1);
    if (q == 0) {
        h2v o;
        o[0] = (_Float16)(p0 * d);
        o[1] = (_Float16)(p1 * d);
        ((h2v*)hs2)[node] = o;
    }
}

// ================= final pull + bias + log_softmax =================

__global__ void k_pull2lsm(const _Float16* __restrict__ hs2, const int* __restrict__ rs,
                           const int* __restrict__ col2, const float* __restrict__ dis,
                           const float* __restrict__ b3, float* __restrict__ out, int n) {
    int node = blockIdx.x * blockDim.x + threadIdx.x;
    if (node >= n) return;
    const h2v* H = (const h2v*)hs2;
    h2v self = H[node];
    float a0 = (float)self[0], a1 = (float)self[1];
    int b = rs[node], e2 = rs[node + 1];
    int i = b;
    for (; i + 3 < e2; i += 4) {
        h2v v0 = H[col2[i]];
        h2v v1 = H[col2[i + 1]];
        h2v v2 = H[col2[i + 2]];
        h2v v3 = H[col2[i + 3]];
        a0 += (float)v0[0] + (float)v1[0] + (float)v2[0] + (float)v3[0];
        a1 += (float)v0[1] + (float)v1[1] + (float)v2[1] + (float)v3[1];
    }
    for (; i < e2; i++) {
        h2v v = H[col2[i]];
        a0 += (float)v[0];
        a1 += (float)v[1];
    }
    float d = dis[node];
    float z0 = a0 * d + b3[0];
    float z1 = a1 * d + b3[1];
    float m = fmaxf(z0, z1);
    float l = m + logf(expf(z0 - m) + expf(z1 - m));
    float2 o = {z0 - l, z1 - l};
    ((float2*)out)[node] = o;
}

// ================= launch =================

extern "C" void kernel_launch(void* const* d_in, const int* in_sizes, int n_in,
                              void* d_out, int out_size, void* d_ws, size_t ws_size,
                              hipStream_t stream) {
    const float* x  = (const float*)d_in[0];
    const int*   ei = (const int*)d_in[1];
    const float* W1 = (const float*)d_in[2];
    const float* b1 = (const float*)d_in[3];
    const float* W2 = (const float*)d_in[4];
    const float* b2 = (const float*)d_in[5];
    const float* W3 = (const float*)d_in[6];
    const float* b3 = (const float*)d_in[7];
    float* out = (float*)d_out;

    const int N = in_sizes[0] / 128;
    const int E = in_sizes[1] / 2;
    const int* src = ei;
    const int* dst = ei + E;

    const int NBUCK = (N + BKN - 1) >> BSH;      // 196 for N=100000
    const int M = NBUCK * NSB;
    const int ES = (E + NSB - 1) / NSB;

    char* ws = (char*)d_ws;
    size_t off = 0;
    auto alloc = [&](size_t bytes) {
        void* p = ws + off;
        off += (bytes + 255) & ~(size_t)255;
        return p;
    };
    int*       hist = (int*)alloc((size_t)M * sizeof(int));
    int*       offs = (int*)alloc((size_t)M * sizeof(int));
    int*       bsum = (int*)alloc(256 * sizeof(int));
    unsigned*  col  = (unsigned*)alloc((size_t)E * sizeof(unsigned));
    int*       col2 = (int*)alloc((size_t)E * sizeof(int));
    int*       rs   = (int*)alloc((size_t)(N + 1) * sizeof(int));
    float*     dis  = (float*)alloc((size_t)N * sizeof(float));
    _Float16*  hsA  = (_Float16*)alloc((size_t)N * 16 * sizeof(_Float16));
    _Float16*  hsB  = (_Float16*)alloc((size_t)N * 16 * sizeof(_Float16));
    _Float16*  hs2  = (_Float16*)alloc((size_t)N * 2 * sizeof(_Float16));

    const int B = 256;
    auto g = [&](long long work) { return (int)((work + B - 1) / B); };
    const int NBS = (M + 2047) / 2048;

    // ---- CSR build: bucket (512-node granularity) + per-bucket counting sort ----
    k_hist<<<NSB, B, 0, stream>>>(dst, hist, E, NBUCK, ES);
    k_scan1<<<NBS, 256, 0, stream>>>(hist, offs, bsum, M);
    k_scan2<<<1, 256, 0, stream>>>(bsum, NBS);
    k_scan3<<<g(M), B, 0, stream>>>(offs, bsum, M);
    k_bucket<<<NSB, B, 0, stream>>>(src, dst, offs, col, E, NBUCK, ES);
    k_sort<<<NBUCK, BKN, 0, stream>>>(col, offs, col2, rs, dis, N, E, NBUCK);

    // ---- layer 1 linear ----
    k_linear1s<<<(N + 15) / 16, B, 0, stream>>>(x, W1, dis, hsA, N);

    // ---- agg1 + layer2 linear (fused) ----
    k_pullA<<<g((long long)N * 2), B, 0, stream>>>(hsA, rs, col2, dis, b1, W2, hsB, N);

    // ---- agg2 + layer3 linear (fused) ----
    k_pullB<<<g((long long)N * 2), B, 0, stream>>>(hsB, rs, col2, dis, b2, W3, hs2, N);

    // ---- agg3 + bias + log_softmax (fused) ----
    k_pull2lsm<<<g(N), B, 0, stream>>>(hs2, rs, col2, dis, b3, out, N);
}

// Round 7
// 283.457 us; speedup vs baseline: 3.0474x; 1.1068x over previous
//
#include <hip/hip_runtime.h>
#include <math.h>

#define NSB  1024  // edge-chunk blocks for hist/bucket passes
#define BSH  9     // 512 nodes per bucket
#define BKN  512   // nodes per bucket
#define TPB  8     // 16-node tiles per block in linear1

typedef _Float16 h8  __attribute__((ext_vector_type(8)));
typedef _Float16 h2v __attribute__((ext_vector_type(2)));

// ================= exclusive scan (n <= 524288) =================

__global__ void k_scan1(const int* __restrict__ in, int* __restrict__ out,
                        int* __restrict__ bsum, int n) {
    __shared__ int sd[256];
    int base = blockIdx.x * 2048 + threadIdx.x * 8;
    int v[8];
    int ts = 0;
#pragma unroll
    for (int j = 0; j < 8; j++) {
        int idx = base + j;
        v[j] = ts;
        ts += (idx < n) ? in[idx] : 0;
    }
    sd[threadIdx.x] = ts;
    __syncthreads();
    for (int ofs = 1; ofs < 256; ofs <<= 1) {
        int t = (threadIdx.x >= (unsigned)ofs) ? sd[threadIdx.x - ofs] : 0;
        __syncthreads();
        sd[threadIdx.x] += t;
        __syncthreads();
    }
    int excl = (threadIdx.x == 0) ? 0 : sd[threadIdx.x - 1];
#pragma unroll
    for (int j = 0; j < 8; j++) {
        int idx = base + j;
        if (idx < n) out[idx] = excl + v[j];
    }
    if (threadIdx.x == 255) bsum[blockIdx.x] = sd[255];
}

__global__ void k_scan2(int* __restrict__ bsum, int nb) {
    __shared__ int sd[256];
    int orig = (threadIdx.x < (unsigned)nb) ? bsum[threadIdx.x] : 0;
    sd[threadIdx.x] = orig;
    __syncthreads();
    for (int ofs = 1; ofs < 256; ofs <<= 1) {
        int t = (threadIdx.x >= (unsigned)ofs) ? sd[threadIdx.x - ofs] : 0;
        __syncthreads();
        sd[threadIdx.x] += t;
        __syncthreads();
    }
    if (threadIdx.x < (unsigned)nb) bsum[threadIdx.x] = sd[threadIdx.x] - orig;
}

__global__ void k_scan3(int* __restrict__ out, const int* __restrict__ bsum, int n) {
    int i = blockIdx.x * blockDim.x + threadIdx.x;
    if (i < n) out[i] += bsum[i >> 11];
}

// ================= bucketing (512-node buckets) =================

__global__ void k_hist(const int* __restrict__ dst, int* __restrict__ hist,
                       int e, int nbuck, int es) {
    __shared__ int h[256];
    for (int i = threadIdx.x; i < 256; i += blockDim.x) h[i] = 0;
    __syncthreads();
    int lo = blockIdx.x * es;
    int hi = min(lo + es, e);
    for (int i = lo + threadIdx.x; i < hi; i += blockDim.x)
        atomicAdd(&h[dst[i] >> BSH], 1);
    __syncthreads();
    for (int i = threadIdx.x; i < nbuck; i += blockDim.x)
        hist[(size_t)i * gridDim.x + blockIdx.x] = h[i];
}

// deterministic scatter into bucket-grouped edge array, packed (src<<9)|dstLocal
__global__ void k_bucket(const int* __restrict__ src, const int* __restrict__ dst,
                         const int* __restrict__ offs, unsigned* __restrict__ col,
                         int e, int nbuck, int es) {
    __shared__ int cur[256];
    for (int i = threadIdx.x; i < nbuck; i += blockDim.x)
        cur[i] = offs[(size_t)i * gridDim.x + blockIdx.x];
    __syncthreads();
    int lo = blockIdx.x * es;
    int hi = min(lo + es, e);
    for (int i = lo + threadIdx.x; i < hi; i += blockDim.x) {
        int d = dst[i];
        int b = d >> BSH;
        int pos = atomicAdd(&cur[b], 1);
        col[pos] = ((unsigned)src[i] << BSH) | (unsigned)(d & (BKN - 1));
    }
}

// per-bucket counting sort by dstLocal -> exact CSR (col2 = src ids, rs = row starts),
// plus degree -> dis. One block (1024 threads) per bucket.
__global__ void k_sort(const unsigned* __restrict__ col, const int* __restrict__ offs,
                       int* __restrict__ col2, int* __restrict__ rs,
                       float* __restrict__ dis, int n, int e, int nbuck) {
    __shared__ int cnt[BKN];
    __shared__ int sd[BKN];
    __shared__ int cur[BKN];
    int tid = threadIdx.x;
    int b = blockIdx.x;
    int lo = offs[(size_t)b * NSB];
    int hi = (b + 1 < nbuck) ? offs[(size_t)(b + 1) * NSB] : e;
    if (tid < BKN) cnt[tid] = 0;
    __syncthreads();
    for (int i = lo + tid; i < hi; i += 1024)
        atomicAdd(&cnt[col[i] & (BKN - 1u)], 1);
    __syncthreads();
    if (tid < BKN) sd[tid] = cnt[tid];
    __syncthreads();
    for (int ofs = 1; ofs < BKN; ofs <<= 1) {
        int t = (tid < BKN && tid >= ofs) ? sd[tid - ofs] : 0;
        __syncthreads();
        if (tid < BKN) sd[tid] += t;
        __syncthreads();
    }
    if (tid < BKN) {
        int excl = (tid == 0) ? 0 : sd[tid - 1];
        cur[tid] = lo + excl;
        int node = (b << BSH) + tid;
        if (node < n) {
            rs[node] = lo + excl;
            dis[node] = rsqrtf((float)(cnt[tid] + 1));
        }
    }
    if (b == 0 && tid == 0) rs[n] = e;
    __syncthreads();
    for (int i = lo + tid; i < hi; i += 1024) {
        unsigned v = col[i];
        int pos = atomicAdd(&cur[v & (BKN - 1u)], 1);
        col2[pos] = (int)(v >> BSH);
    }
}

// ================= layer-1 linear: hs[n,16] = (x @ W1) * dis, fp16 out =================
// 8 tiles of 16 nodes per block; W transposed in LDS; 132-float padded rows so both
// operands stream via ds_read_b128.

__global__ void k_linear1s(const float* __restrict__ x, const float* __restrict__ W,
                           const float* __restrict__ dis, _Float16* __restrict__ hs,
                           int n, int ntiles) {
    __shared__ float sWT[16 * 132];
    __shared__ float sx[16 * 132];
    int tid = threadIdx.x;
    // stage W transposed: W[k][c] -> sWT[c*132 + k]
    for (int i = tid; i < 2048; i += 256) {
        int k = i >> 4, c = i & 15;
        sWT[c * 132 + k] = W[i];
    }
    int tile0 = blockIdx.x * TPB;
    const float4* xg4 = (const float4*)x;
    for (int tile = tile0; tile < tile0 + TPB && tile < ntiles; tile++) {
        int nodeBase = tile * 16;
        __syncthreads();   // protect sx from previous iteration's readers
        for (int i = tid; i < 512; i += 256) {
            int nl = i >> 5, k4 = i & 31;   // 32 float4 per 128-float row
            int nd = nodeBase + nl;
            float4 v = make_float4(0.f, 0.f, 0.f, 0.f);
            if (nd < n) v = xg4[(size_t)nd * 32 + k4];
            *((float4*)(sx + nl * 132 + k4 * 4)) = v;
        }
        __syncthreads();
        int nl = tid >> 4, c = tid & 15;
        int node = nodeBase + nl;
        const float4* xr = (const float4*)(sx + nl * 132);
        const float4* wr = (const float4*)(sWT + c * 132);
        float acc = 0.f;
#pragma unroll
        for (int k4 = 0; k4 < 32; k4++) {
            float4 xv = xr[k4];
            float4 wv = wr[k4];
            acc += xv.x * wv.x + xv.y * wv.y + xv.z * wv.z + xv.w * wv.w;
        }
        if (node < n)
            hs[(size_t)node * 16 + c] = (_Float16)(acc * dis[node]);
    }
}

// ================= fused pull + 16x16 linear =================
// agg[u] = dis[u]*(hs[u] + sum_{v->u} hs[v]); hsOut[u] = (relu(agg+b) @ W) * dis[u]
// 2 threads per node (q = half of the 16-wide row). Pair-exchange of the 8 relu'd
// activations via shfl_xor(1); each lane then does the full 16-k dot for its 8 outputs.

__global__ void k_pullA(const _Float16* __restrict__ hs, const int* __restrict__ rs,
                        const int* __restrict__ col2, const float* __restrict__ dis,
                        const float* __restrict__ bb, const float* __restrict__ W,
                        _Float16* __restrict__ hsOut, int n) {
    __shared__ float sW[256];
    __shared__ float sb[16];
    if (threadIdx.x < 256) sW[threadIdx.x] = W[threadIdx.x];
    if (threadIdx.x < 16) sb[threadIdx.x] = bb[threadIdx.x];
    __syncthreads();
    int t = blockIdx.x * blockDim.x + threadIdx.x;
    int node = t >> 1, q = t & 1;
    if (node >= n) return;
    const h8* H = (const h8*)hs;
    h8 self = H[(size_t)node * 2 + q];
    float acc[8];
#pragma unroll
    for (int j = 0; j < 8; j++) acc[j] = (float)self[j];
    int b = rs[node], e2 = rs[node + 1];
    int i = b;
    for (; i + 3 < e2; i += 4) {
        int s0 = col2[i], s1 = col2[i + 1], s2 = col2[i + 2], s3 = col2[i + 3];
        h8 v0 = H[(size_t)s0 * 2 + q];
        h8 v1 = H[(size_t)s1 * 2 + q];
        h8 v2 = H[(size_t)s2 * 2 + q];
        h8 v3 = H[(size_t)s3 * 2 + q];
#pragma unroll
        for (int j = 0; j < 8; j++)
            acc[j] += (float)v0[j] + (float)v1[j] + (float)v2[j] + (float)v3[j];
    }
    for (; i < e2; i++) {
        h8 v = H[(size_t)col2[i] * 2 + q];
#pragma unroll
        for (int j = 0; j < 8; j++) acc[j] += (float)v[j];
    }
    float d = dis[node];
    float va[16];
#pragma unroll
    for (int j = 0; j < 8; j++) {
        int k = q * 8 + j;
        float v = acc[j] * d + sb[k];
        v = v > 0.f ? v : 0.f;
        float other = __shfl_xor(v, 1);
        va[j]     = q ? other : v;      // channel j     (lane q=0's k-range)
        va[8 + j] = q ? v : other;      // channel 8+j   (lane q=1's k-range)
    }
    h8 o;
#pragma unroll
    for (int j = 0; j < 8; j++) {
        int c = q * 8 + j;              // this lane's output channel
        float s = 0.f;
#pragma unroll
        for (int k = 0; k < 16; k++) s += va[k] * sW[k * 16 + c];
        o[j] = (_Float16)(s * d);
    }
    ((h8*)hsOut)[(size_t)node * 2 + q] = o;
}

// ================= fused pull + 16x2 linear (layer 3 transform) =================

__global__ void k_pullB(const _Float16* __restrict__ hs, const int* __restrict__ rs,
                        const int* __restrict__ col2, const float* __restrict__ dis,
                        const float* __restrict__ bb, const float* __restrict__ W,
                        _Float16* __restrict__ hs2, int n) {
    __shared__ float sW[32];
    __shared__ float sb[16];
    if (threadIdx.x < 32) sW[threadIdx.x] = W[threadIdx.x];
    if (threadIdx.x < 16) sb[threadIdx.x] = bb[threadIdx.x];
    __syncthreads();
    int t = blockIdx.x * blockDim.x + threadIdx.x;
    int node = t >> 1, q = t & 1;
    if (node >= n) return;
    const h8* H = (const h8*)hs;
    h8 self = H[(size_t)node * 2 + q];
    float acc[8];
#pragma unroll
    for (int j = 0; j < 8; j++) acc[j] = (float)self[j];
    int b = rs[node], e2 = rs[node + 1];
    int i = b;
    for (; i + 3 < e2; i += 4) {
        int s0 = col2[i], s1 = col2[i + 1], s2 = col2[i + 2], s3 = col2[i + 3];
        h8 v0 = H[(size_t)s0 * 2 + q];
        h8 v1 = H[(size_t)s1 * 2 + q];
        h8 v2 = H[(size_t)s2 * 2 + q];
        h8 v3 = H[(size_t)s3 * 2 + q];
#pragma unroll
        for (int j = 0; j < 8; j++)
            acc[j] += (float)v0[j] + (float)v1[j] + (float)v2[j] + (float)v3[j];
    }
    for (; i < e2; i++) {
        h8 v = H[(size_t)col2[i] * 2 + q];
#pragma unroll
        for (int j = 0; j < 8; j++) acc[j] += (float)v[j];
    }
    float d = dis[node];
    float p0 = 0.f, p1 = 0.f;
#pragma unroll
    for (int j = 0; j < 8; j++) {
        int k = q * 8 + j;
        float v = acc[j] * d + sb[k];
        v = v > 0.f ? v : 0.f;
        p0 += v * sW[k * 2 + 0];
        p1 += v * sW[k * 2 + 1];
    }
    p0 += __shfl_xor(p0, 1);   // same channel on both lanes -> symmetric, safe
    p1 += __shfl_xor(p1, 1);
    if (q == 0) {
        h2v o;
        o[0] = (_Float16)(p0 * d);
        o[1] = (_Float16)(p1 * d);
        ((h2v*)hs2)[node] = o;
    }
}

// ================= final pull + bias + log_softmax =================

__global__ void k_pull2lsm(const _Float16* __restrict__ hs2, const int* __restrict__ rs,
                           const int* __restrict__ col2, const float* __restrict__ dis,
                           const float* __restrict__ b3, float* __restrict__ out, int n) {
    int node = blockIdx.x * blockDim.x + threadIdx.x;
    if (node >= n) return;
    const h2v* H = (const h2v*)hs2;
    h2v self = H[node];
    float a0 = (float)self[0], a1 = (float)self[1];
    int b = rs[node], e2 = rs[node + 1];
    int i = b;
    for (; i + 3 < e2; i += 4) {
        h2v v0 = H[col2[i]];
        h2v v1 = H[col2[i + 1]];
        h2v v2 = H[col2[i + 2]];
        h2v v3 = H[col2[i + 3]];
        a0 += (float)v0[0] + (float)v1[0] + (float)v2[0] + (float)v3[0];
        a1 += (float)v0[1] + (float)v1[1] + (float)v2[1] + (float)v3[1];
    }
    for (; i < e2; i++) {
        h2v v = H[col2[i]];
        a0 += (float)v[0];
        a1 += (float)v[1];
    }
    float d = dis[node];
    float z0 = a0 * d + b3[0];
    float z1 = a1 * d + b3[1];
    float m = fmaxf(z0, z1);
    float l = m + logf(expf(z0 - m) + expf(z1 - m));
    float2 o = {z0 - l, z1 - l};
    ((float2*)out)[node] = o;
}

// ================= launch =================

extern "C" void kernel_launch(void* const* d_in, const int* in_sizes, int n_in,
                              void* d_out, int out_size, void* d_ws, size_t ws_size,
                              hipStream_t stream) {
    const float* x  = (const float*)d_in[0];
    const int*   ei = (const int*)d_in[1];
    const float* W1 = (const float*)d_in[2];
    const float* b1 = (const float*)d_in[3];
    const float* W2 = (const float*)d_in[4];
    const float* b2 = (const float*)d_in[5];
    const float* W3 = (const float*)d_in[6];
    const float* b3 = (const float*)d_in[7];
    float* out = (float*)d_out;

    const int N = in_sizes[0] / 128;
    const int E = in_sizes[1] / 2;
    const int* src = ei;
    const int* dst = ei + E;

    const int NBUCK = (N + BKN - 1) >> BSH;      // 196 for N=100000
    const int M = NBUCK * NSB;                   // 200704
    const int ES = (E + NSB - 1) / NSB;          // ~3125

    char* ws = (char*)d_ws;
    size_t off = 0;
    auto alloc = [&](size_t bytes) {
        void* p = ws + off;
        off += (bytes + 255) & ~(size_t)255;
        return p;
    };
    int*       hist = (int*)alloc((size_t)M * sizeof(int));
    int*       offs = (int*)alloc((size_t)M * sizeof(int));
    int*       bsum = (int*)alloc(256 * sizeof(int));
    unsigned*  col  = (unsigned*)alloc((size_t)E * sizeof(unsigned));
    int*       col2 = (int*)alloc((size_t)E * sizeof(int));
    int*       rs   = (int*)alloc((size_t)(N + 1) * sizeof(int));
    float*     dis  = (float*)alloc((size_t)N * sizeof(float));
    _Float16*  hsA  = (_Float16*)alloc((size_t)N * 16 * sizeof(_Float16));
    _Float16*  hsB  = (_Float16*)alloc((size_t)N * 16 * sizeof(_Float16));
    _Float16*  hs2  = (_Float16*)alloc((size_t)N * 2 * sizeof(_Float16));

    const int B = 256;
    auto g = [&](long long work) { return (int)((work + B - 1) / B); };
    const int NBS = (M + 2047) / 2048;           // 98 <= 256

    // ---- CSR build: bucket (512-node granularity) + per-bucket counting sort ----
    k_hist<<<NSB, B, 0, stream>>>(dst, hist, E, NBUCK, ES);
    k_scan1<<<NBS, 256, 0, stream>>>(hist, offs, bsum, M);
    k_scan2<<<1, 256, 0, stream>>>(bsum, NBS);
    k_scan3<<<g(M), B, 0, stream>>>(offs, bsum, M);
    k_bucket<<<NSB, B, 0, stream>>>(src, dst, offs, col, E, NBUCK, ES);
    k_sort<<<NBUCK, 1024, 0, stream>>>(col, offs, col2, rs, dis, N, E, NBUCK);

    // ---- layer 1 linear ----
    const int NTILES = (N + 15) / 16;
    k_linear1s<<<(NTILES + TPB - 1) / TPB, B, 0, stream>>>(x, W1, dis, hsA, N, NTILES);

    // ---- agg1 + layer2 linear (fused) ----
    k_pullA<<<g((long long)N * 2), B, 0, stream>>>(hsA, rs, col2, dis, b1, W2, hsB, N);

    // ---- agg2 + layer3 linear (fused) ----
    k_pullB<<<g((long long)N * 2), B, 0, stream>>>(hsB, rs, col2, dis, b2, W3, hs2, N);

    // ---- agg3 + bias + log_softmax (fused) ----
    k_pull2lsm<<<g(N), B, 0, stream>>>(hs2, rs, col2, dis, b3, out, N);
}

// Round 8
// 281.377 us; speedup vs baseline: 3.0699x; 1.0074x over previous
//
#include <hip/hip_runtime.h>
#include <math.h>

#define NSB  512   // edge-chunk blocks for hist/bucket passes
#define BSH  9     // 512 nodes per bucket
#define BKN  512   // nodes per bucket
#define ESMAX 6272 // max edges per chunk block (E/NSB <= this; 3.2M/512 = 6250)
#define TPB  8     // 16-node tiles per block in linear1

typedef _Float16 h8  __attribute__((ext_vector_type(8)));
typedef _Float16 h2v __attribute__((ext_vector_type(2)));

// ================= exclusive scan (n <= 524288) =================

__global__ void k_scan1(const int* __restrict__ in, int* __restrict__ out,
                        int* __restrict__ bsum, int n) {
    __shared__ int sd[256];
    int base = blockIdx.x * 2048 + threadIdx.x * 8;
    int v[8];
    int ts = 0;
#pragma unroll
    for (int j = 0; j < 8; j++) {
        int idx = base + j;
        v[j] = ts;
        ts += (idx < n) ? in[idx] : 0;
    }
    sd[threadIdx.x] = ts;
    __syncthreads();
    for (int ofs = 1; ofs < 256; ofs <<= 1) {
        int t = (threadIdx.x >= (unsigned)ofs) ? sd[threadIdx.x - ofs] : 0;
        __syncthreads();
        sd[threadIdx.x] += t;
        __syncthreads();
    }
    int excl = (threadIdx.x == 0) ? 0 : sd[threadIdx.x - 1];
#pragma unroll
    for (int j = 0; j < 8; j++) {
        int idx = base + j;
        if (idx < n) out[idx] = excl + v[j];
    }
    if (threadIdx.x == 255) bsum[blockIdx.x] = sd[255];
}

__global__ void k_scan2(int* __restrict__ bsum, int nb) {
    __shared__ int sd[256];
    int orig = (threadIdx.x < (unsigned)nb) ? bsum[threadIdx.x] : 0;
    sd[threadIdx.x] = orig;
    __syncthreads();
    for (int ofs = 1; ofs < 256; ofs <<= 1) {
        int t = (threadIdx.x >= (unsigned)ofs) ? sd[threadIdx.x - ofs] : 0;
        __syncthreads();
        sd[threadIdx.x] += t;
        __syncthreads();
    }
    if (threadIdx.x < (unsigned)nb) bsum[threadIdx.x] = sd[threadIdx.x] - orig;
}

__global__ void k_scan3(int* __restrict__ out, const int* __restrict__ bsum, int n) {
    int i = blockIdx.x * blockDim.x + threadIdx.x;
    if (i < n) out[i] += bsum[i >> 11];
}

// ================= bucketing (512-node buckets) =================

__global__ void k_hist(const int* __restrict__ dst, int* __restrict__ hist,
                       int e, int nbuck, int es) {
    __shared__ int h[256];
    for (int i = threadIdx.x; i < 256; i += blockDim.x) h[i] = 0;
    __syncthreads();
    int lo = blockIdx.x * es;
    int hi = min(lo + es, e);
    for (int i = lo + threadIdx.x; i < hi; i += blockDim.x)
        atomicAdd(&h[dst[i] >> BSH], 1);
    __syncthreads();
    for (int i = threadIdx.x; i < nbuck; i += blockDim.x)
        hist[(size_t)i * gridDim.x + blockIdx.x] = h[i];
}

// LDS-local counting sort by bucket, then contiguous run writes -> coalesced col stores.
// Requires nbuck <= 256 and chunk size <= ESMAX. blockDim = 256.
__global__ void k_bucket(const int* __restrict__ src, const int* __restrict__ dst,
                         const int* __restrict__ offs, unsigned* __restrict__ col,
                         int e, int nbuck, int es) {
    __shared__ unsigned sorted[ESMAX];
    __shared__ unsigned char sbuck[ESMAX];
    __shared__ int lc[256], lsc[256], lofE[256], lcur[256], soff[256];
    int tid = threadIdx.x;
    lc[tid] = 0;
    if (tid < nbuck) soff[tid] = offs[(size_t)tid * gridDim.x + blockIdx.x];
    __syncthreads();
    int lo = blockIdx.x * es;
    int hi = min(lo + es, e);
    // pass 1: local histogram
    for (int i = lo + tid; i < hi; i += 256)
        atomicAdd(&lc[dst[i] >> BSH], 1);
    __syncthreads();
    // local scan
    lsc[tid] = lc[tid];
    __syncthreads();
    for (int ofs = 1; ofs < 256; ofs <<= 1) {
        int t = (tid >= ofs) ? lsc[tid - ofs] : 0;
        __syncthreads();
        lsc[tid] += t;
        __syncthreads();
    }
    int excl = (tid == 0) ? 0 : lsc[tid - 1];
    lofE[tid] = excl;
    lcur[tid] = excl;
    __syncthreads();
    // pass 2: scatter into LDS (sorted by bucket)
    for (int i = lo + tid; i < hi; i += 256) {
        int d = dst[i];
        int b = d >> BSH;
        int p = atomicAdd(&lcur[b], 1);
        sorted[p] = ((unsigned)src[i] << BSH) | (unsigned)(d & (BKN - 1));
        sbuck[p] = (unsigned char)b;
    }
    __syncthreads();
    // pass 3: linear sweep -> contiguous per-run global writes (wave-coalesced)
    int cnt = hi - lo;
    for (int i = tid; i < cnt; i += 256) {
        int b = sbuck[i];
        col[soff[b] + (i - lofE[b])] = sorted[i];
    }
}

// per-bucket counting sort by dstLocal -> exact CSR (col2 = src ids, rs = row starts),
// plus degree -> dis. One block (1024 threads) per bucket.
__global__ void k_sort(const unsigned* __restrict__ col, const int* __restrict__ offs,
                       int* __restrict__ col2, int* __restrict__ rs,
                       float* __restrict__ dis, int n, int e, int nbuck) {
    __shared__ int cnt[BKN];
    __shared__ int sd[BKN];
    __shared__ int cur[BKN];
    int tid = threadIdx.x;
    int b = blockIdx.x;
    int lo = offs[(size_t)b * NSB];
    int hi = (b + 1 < nbuck) ? offs[(size_t)(b + 1) * NSB] : e;
    if (tid < BKN) cnt[tid] = 0;
    __syncthreads();
    for (int i = lo + tid; i < hi; i += 1024)
        atomicAdd(&cnt[col[i] & (BKN - 1u)], 1);
    __syncthreads();
    if (tid < BKN) sd[tid] = cnt[tid];
    __syncthreads();
    for (int ofs = 1; ofs < BKN; ofs <<= 1) {
        int t = (tid < BKN && tid >= ofs) ? sd[tid - ofs] : 0;
        __syncthreads();
        if (tid < BKN) sd[tid] += t;
        __syncthreads();
    }
    if (tid < BKN) {
        int excl = (tid == 0) ? 0 : sd[tid - 1];
        cur[tid] = lo + excl;
        int node = (b << BSH) + tid;
        if (node < n) {
            rs[node] = lo + excl;
            dis[node] = rsqrtf((float)(cnt[tid] + 1));
        }
    }
    if (b == 0 && tid == 0) rs[n] = e;
    __syncthreads();
    for (int i = lo + tid; i < hi; i += 1024) {
        unsigned v = col[i];
        int pos = atomicAdd(&cur[v & (BKN - 1u)], 1);
        col2[pos] = (int)(v >> BSH);
    }
}

// ================= layer-1 linear: hs[n,16] = (x @ W1) * dis, fp16 out =================
// 8 tiles of 16 nodes per block; W transposed in LDS; 132-float padded rows so both
// operands stream via ds_read_b128.

__global__ void k_linear1s(const float* __restrict__ x, const float* __restrict__ W,
                           const float* __restrict__ dis, _Float16* __restrict__ hs,
                           int n, int ntiles) {
    __shared__ float sWT[16 * 132];
    __shared__ float sx[16 * 132];
    int tid = threadIdx.x;
    // stage W transposed: W[k][c] -> sWT[c*132 + k]
    for (int i = tid; i < 2048; i += 256) {
        int k = i >> 4, c = i & 15;
        sWT[c * 132 + k] = W[i];
    }
    int tile0 = blockIdx.x * TPB;
    const float4* xg4 = (const float4*)x;
    for (int tile = tile0; tile < tile0 + TPB && tile < ntiles; tile++) {
        int nodeBase = tile * 16;
        __syncthreads();   // protect sx from previous iteration's readers
        for (int i = tid; i < 512; i += 256) {
            int nl = i >> 5, k4 = i & 31;   // 32 float4 per 128-float row
            int nd = nodeBase + nl;
            float4 v = make_float4(0.f, 0.f, 0.f, 0.f);
            if (nd < n) v = xg4[(size_t)nd * 32 + k4];
            *((float4*)(sx + nl * 132 + k4 * 4)) = v;
        }
        __syncthreads();
        int nl = tid >> 4, c = tid & 15;
        int node = nodeBase + nl;
        const float4* xr = (const float4*)(sx + nl * 132);
        const float4* wr = (const float4*)(sWT + c * 132);
        float acc = 0.f;
#pragma unroll
        for (int k4 = 0; k4 < 32; k4++) {
            float4 xv = xr[k4];
            float4 wv = wr[k4];
            acc += xv.x * wv.x + xv.y * wv.y + xv.z * wv.z + xv.w * wv.w;
        }
        if (node < n)
            hs[(size_t)node * 16 + c] = (_Float16)(acc * dis[node]);
    }
}

// ================= fused pull + 16x16 linear =================
// agg[u] = dis[u]*(hs[u] + sum_{v->u} hs[v]); hsOut[u] = (relu(agg+b) @ W) * dis[u]
// 2 threads per node (q = half of the 16-wide row). Pair-exchange of the 8 relu'd
// activations via shfl_xor(1); each lane then does the full 16-k dot for its 8 outputs.

__global__ void k_pullA(const _Float16* __restrict__ hs, const int* __restrict__ rs,
                        const int* __restrict__ col2, const float* __restrict__ dis,
                        const float* __restrict__ bb, const float* __restrict__ W,
                        _Float16* __restrict__ hsOut, int n) {
    __shared__ float sW[256];
    __shared__ float sb[16];
    if (threadIdx.x < 256) sW[threadIdx.x] = W[threadIdx.x];
    if (threadIdx.x < 16) sb[threadIdx.x] = bb[threadIdx.x];
    __syncthreads();
    int t = blockIdx.x * blockDim.x + threadIdx.x;
    int node = t >> 1, q = t & 1;
    if (node >= n) return;
    const h8* H = (const h8*)hs;
    h8 self = H[(size_t)node * 2 + q];
    float acc[8];
#pragma unroll
    for (int j = 0; j < 8; j++) acc[j] = (float)self[j];
    int b = rs[node], e2 = rs[node + 1];
    int i = b;
    for (; i + 3 < e2; i += 4) {
        int s0 = col2[i], s1 = col2[i + 1], s2 = col2[i + 2], s3 = col2[i + 3];
        h8 v0 = H[(size_t)s0 * 2 + q];
        h8 v1 = H[(size_t)s1 * 2 + q];
        h8 v2 = H[(size_t)s2 * 2 + q];
        h8 v3 = H[(size_t)s3 * 2 + q];
#pragma unroll
        for (int j = 0; j < 8; j++)
            acc[j] += (float)v0[j] + (float)v1[j] + (float)v2[j] + (float)v3[j];
    }
    for (; i < e2; i++) {
        h8 v = H[(size_t)col2[i] * 2 + q];
#pragma unroll
        for (int j = 0; j < 8; j++) acc[j] += (float)v[j];
    }
    float d = dis[node];
    float va[16];
#pragma unroll
    for (int j = 0; j < 8; j++) {
        int k = q * 8 + j;
        float v = acc[j] * d + sb[k];
        v = v > 0.f ? v : 0.f;
        float other = __shfl_xor(v, 1);
        va[j]     = q ? other : v;      // channel j     (lane q=0's k-range)
        va[8 + j] = q ? v : other;      // channel 8+j   (lane q=1's k-range)
    }
    h8 o;
#pragma unroll
    for (int j = 0; j < 8; j++) {
        int c = q * 8 + j;              // this lane's output channel
        float s = 0.f;
#pragma unroll
        for (int k = 0; k < 16; k++) s += va[k] * sW[k * 16 + c];
        o[j] = (_Float16)(s * d);
    }
    ((h8*)hsOut)[(size_t)node * 2 + q] = o;
}

// ================= fused pull + 16x2 linear (layer 3 transform) =================

__global__ void k_pullB(const _Float16* __restrict__ hs, const int* __restrict__ rs,
                        const int* __restrict__ col2, const float* __restrict__ dis,
                        const float* __restrict__ bb, const float* __restrict__ W,
                        _Float16* __restrict__ hs2, int n) {
    __shared__ float sW[32];
    __shared__ float sb[16];
    if (threadIdx.x < 32) sW[threadIdx.x] = W[threadIdx.x];
    if (threadIdx.x < 16) sb[threadIdx.x] = bb[threadIdx.x];
    __syncthreads();
    int t = blockIdx.x * blockDim.x + threadIdx.x;
    int node = t >> 1, q = t & 1;
    if (node >= n) return;
    const h8* H = (const h8*)hs;
    h8 self = H[(size_t)node * 2 + q];
    float acc[8];
#pragma unroll
    for (int j = 0; j < 8; j++) acc[j] = (float)self[j];
    int b = rs[node], e2 = rs[node + 1];
    int i = b;
    for (; i + 3 < e2; i += 4) {
        int s0 = col2[i], s1 = col2[i + 1], s2 = col2[i + 2], s3 = col2[i + 3];
        h8 v0 = H[(size_t)s0 * 2 + q];
        h8 v1 = H[(size_t)s1 * 2 + q];
        h8 v2 = H[(size_t)s2 * 2 + q];
        h8 v3 = H[(size_t)s3 * 2 + q];
#pragma unroll
        for (int j = 0; j < 8; j++)
            acc[j] += (float)v0[j] + (float)v1[j] + (float)v2[j] + (float)v3[j];
    }
    for (; i < e2; i++) {
        h8 v = H[(size_t)col2[i] * 2 + q];
#pragma unroll
        for (int j = 0; j < 8; j++) acc[j] += (float)v[j];
    }
    float d = dis[node];
    float p0 = 0.f, p1 = 0.f;
#pragma unroll
    for (int j = 0; j < 8; j++) {
        int k = q * 8 + j;
        float v = acc[j] * d + sb[k];
        v = v > 0.f ? v : 0.f;
        p0 += v * sW[k * 2 + 0];
        p1 += v * sW[k * 2 + 1];
    }
    p0 += __shfl_xor(p0, 1);   // same channel on both lanes -> symmetric, safe
    p1 += __shfl_xor(p1, 1);
    if (q == 0) {
        h2v o;
        o[0] = (_Float16)(p0 * d);
        o[1] = (_Float16)(p1 * d);
        ((h2v*)hs2)[node] = o;
    }
}

// ================= final pull + bias + log_softmax =================

__global__ void k_pull2lsm(const _Float16* __restrict__ hs2, const int* __restrict__ rs,
                           const int* __restrict__ col2, const float* __restrict__ dis,
                           const float* __restrict__ b3, float* __restrict__ out, int n) {
    int node = blockIdx.x * blockDim.x + threadIdx.x;
    if (node >= n) return;
    const h2v* H = (const h2v*)hs2;
    h2v self = H[node];
    float a0 = (float)self[0], a1 = (float)self[1];
    int b = rs[node], e2 = rs[node + 1];
    int i = b;
    for (; i + 3 < e2; i += 4) {
        h2v v0 = H[col2[i]];
        h2v v1 = H[col2[i + 1]];
        h2v v2 = H[col2[i + 2]];
        h2v v3 = H[col2[i + 3]];
        a0 += (float)v0[0] + (float)v1[0] + (float)v2[0] + (float)v3[0];
        a1 += (float)v0[1] + (float)v1[1] + (float)v2[1] + (float)v3[1];
    }
    for (; i < e2; i++) {
        h2v v = H[col2[i]];
        a0 += (float)v[0];
        a1 += (float)v[1];
    }
    float d = dis[node];
    float z0 = a0 * d + b3[0];
    float z1 = a1 * d + b3[1];
    float m = fmaxf(z0, z1);
    float l = m + logf(expf(z0 - m) + expf(z1 - m));
    float2 o = {z0 - l, z1 - l};
    ((float2*)out)[node] = o;
}

// ================= launch =================

extern "C" void kernel_launch(void* const* d_in, const int* in_sizes, int n_in,
                              void* d_out, int out_size, void* d_ws, size_t ws_size,
                              hipStream_t stream) {
    const float* x  = (const float*)d_in[0];
    const int*   ei = (const int*)d_in[1];
    const float* W1 = (const float*)d_in[2];
    const float* b1 = (const float*)d_in[3];
    const float* W2 = (const float*)d_in[4];
    const float* b2 = (const float*)d_in[5];
    const float* W3 = (const float*)d_in[6];
    const float* b3 = (const float*)d_in[7];
    float* out = (float*)d_out;

    const int N = in_sizes[0] / 128;
    const int E = in_sizes[1] / 2;
    const int* src = ei;
    const int* dst = ei + E;

    const int NBUCK = (N + BKN - 1) >> BSH;      // 196 for N=100000 (must be <= 256)
    const int M = NBUCK * NSB;                   // 100352
    const int ES = (E + NSB - 1) / NSB;          // 6250 (must be <= ESMAX)

    char* ws = (char*)d_ws;
    size_t off = 0;
    auto alloc = [&](size_t bytes) {
        void* p = ws + off;
        off += (bytes + 255) & ~(size_t)255;
        return p;
    };
    int*       hist = (int*)alloc((size_t)M * sizeof(int));
    int*       offs = (int*)alloc((size_t)M * sizeof(int));
    int*       bsum = (int*)alloc(256 * sizeof(int));
    unsigned*  col  = (unsigned*)alloc((size_t)E * sizeof(unsigned));
    int*       col2 = (int*)alloc((size_t)E * sizeof(int));
    int*       rs   = (int*)alloc((size_t)(N + 1) * sizeof(int));
    float*     dis  = (float*)alloc((size_t)N * sizeof(float));
    _Float16*  hsA  = (_Float16*)alloc((size_t)N * 16 * sizeof(_Float16));
    _Float16*  hsB  = (_Float16*)alloc((size_t)N * 16 * sizeof(_Float16));
    _Float16*  hs2  = (_Float16*)alloc((size_t)N * 2 * sizeof(_Float16));

    const int B = 256;
    auto g = [&](long long work) { return (int)((work + B - 1) / B); };
    const int NBS = (M + 2047) / 2048;           // 49 <= 256

    // ---- CSR build: bucket (512-node granularity) + per-bucket counting sort ----
    k_hist<<<NSB, B, 0, stream>>>(dst, hist, E, NBUCK, ES);
    k_scan1<<<NBS, 256, 0, stream>>>(hist, offs, bsum, M);
    k_scan2<<<1, 256, 0, stream>>>(bsum, NBS);
    k_scan3<<<g(M), B, 0, stream>>>(offs, bsum, M);
    k_bucket<<<NSB, B, 0, stream>>>(src, dst, offs, col, E, NBUCK, ES);
    k_sort<<<NBUCK, 1024, 0, stream>>>(col, offs, col2, rs, dis, N, E, NBUCK);

    // ---- layer 1 linear ----
    const int NTILES = (N + 15) / 16;
    k_linear1s<<<(NTILES + TPB - 1) / TPB, B, 0, stream>>>(x, W1, dis, hsA, N, NTILES);

    // ---- agg1 + layer2 linear (fused) ----
    k_pullA<<<g((long long)N * 2), B, 0, stream>>>(hsA, rs, col2, dis, b1, W2, hsB, N);

    // ---- agg2 + layer3 linear (fused) ----
    k_pullB<<<g((long long)N * 2), B, 0, stream>>>(hsB, rs, col2, dis, b2, W3, hs2, N);

    // ---- agg3 + bias + log_softmax (fused) ----
    k_pull2lsm<<<g(N), B, 0, stream>>>(hs2, rs, col2, dis, b3, out, N);
}